// Round 1
// baseline (803.287 us; speedup 1.0000x reference)
//
#include <hip/hip_runtime.h>

typedef unsigned short u16;
typedef unsigned int u32;
typedef __attribute__((ext_vector_type(8))) short bf16x8;
typedef __attribute__((ext_vector_type(4))) float f32x4;

namespace {

constexpr int S = 1024, D = 1024, H = 16, DK = 64;
constexpr float NEGF = -1e30f;

__device__ __forceinline__ u16 f2bf(float f){
  u32 u = __builtin_bit_cast(u32, f);
  u32 r = (u + 0x7fffu + ((u >> 16) & 1u)) >> 16;
  return (u16)r;
}
__device__ __forceinline__ float bf2f(u16 h){
  u32 u = ((u32)h) << 16;
  return __builtin_bit_cast(float, u);
}
__device__ __forceinline__ u32 pack2(float a, float b){
  return (u32)f2bf(a) | ((u32)f2bf(b) << 16);
}

// ---------------------------------------------------------------- seg scan
// segd[b*S+s] = (cumsum(id==SEP) << 2) | (id==CLS)<<1 | (id!=PAD)
__global__ void seg_kernel(const int* __restrict__ ids, int* __restrict__ segd){
  __shared__ int sc[1024];
  int b = blockIdx.x, t = threadIdx.x;
  int id = ids[b*S + t];
  sc[t] = (id == 1) ? 1 : 0;
  __syncthreads();
  for(int off = 1; off < 1024; off <<= 1){
    int add = (t >= off) ? sc[t - off] : 0;
    __syncthreads();
    sc[t] += add;
    __syncthreads();
  }
  int seg = sc[t];
  segd[b*S + t] = (seg << 2) | ((id == 2) ? 2 : 0) | ((id != 0) ? 1 : 0);
}

// ---------------------------------------------------------------- layernorm
__global__ __launch_bounds__(256) void ln_kernel(const float* __restrict__ x,
    const float* __restrict__ w, const float* __restrict__ bias, u16* __restrict__ out){
  int row = blockIdx.x, t = threadIdx.x;
  float4 v = ((const float4*)(x + (size_t)row*D))[t];
  float s = v.x + v.y + v.z + v.w;
  float q = v.x*v.x + v.y*v.y + v.z*v.z + v.w*v.w;
  for(int off = 32; off >= 1; off >>= 1){ s += __shfl_down(s, off); q += __shfl_down(q, off); }
  __shared__ float ls[4], lq[4];
  int wv = t >> 6, ln = t & 63;
  if(ln == 0){ ls[wv] = s; lq[wv] = q; }
  __syncthreads();
  s = ls[0] + ls[1] + ls[2] + ls[3];
  q = lq[0] + lq[1] + lq[2] + lq[3];
  float mean = s * (1.f/D);
  float var  = q * (1.f/D) - mean*mean;
  float rs = rsqrtf(var + 1e-5f);
  float4 wv4 = ((const float4*)w)[t];
  float4 bv4 = ((const float4*)bias)[t];
  ushort4 o;
  o.x = f2bf((v.x-mean)*rs*wv4.x + bv4.x);
  o.y = f2bf((v.y-mean)*rs*wv4.y + bv4.y);
  o.z = f2bf((v.z-mean)*rs*wv4.z + bv4.z);
  o.w = f2bf((v.w-mean)*rs*wv4.w + bv4.w);
  *(ushort4*)(out + (size_t)row*D + t*4) = o;
}

// ---------------------------------------------------------------- head proj (gate / a_proj), N=16
template<bool SIG>
__global__ __launch_bounds__(256) void headproj_kernel(const u16* __restrict__ xln,
    const float* __restrict__ w, const float* __restrict__ bias, float* __restrict__ out){
  __shared__ u16 xrow[D];
  int row = blockIdx.x, t = threadIdx.x;
  ((ushort4*)xrow)[t] = ((const ushort4*)(xln + (size_t)row*D))[t];
  __syncthreads();
  int h = t >> 4, sg = t & 15;
  const u16* xp = xrow + sg*64;
  const float* wp = w + (size_t)h*D + sg*64;
  float acc = 0.f;
  #pragma unroll
  for(int c = 0; c < 64; ++c) acc += bf2f(xp[c]) * wp[c];
  for(int off = 1; off < 16; off <<= 1) acc += __shfl_xor(acc, off);
  if(sg == 0){
    float r = acc + (bias ? bias[h] : 0.f);
    out[(size_t)row*H + h] = SIG ? (1.f/(1.f + __expf(-r))) : r;
  }
}

// ---------------------------------------------------------------- GEMM: C[M,N] = A[M,K](bf16) @ W[N,K](f32)^T + bias
// MODE 0: bf16 natural; MODE 1: bf16 transposed (Vt[b,d,s]); MODE 2: f32 + residual
template<int MODE>
__global__ __launch_bounds__(256) void gemm_kernel(const u16* __restrict__ A,
    const float* __restrict__ W, const float* __restrict__ bias,
    void* __restrict__ outp, const float* __restrict__ resid){
  constexpr int N = 1024, K = 1024;
  __shared__ u16 As[128][40];   // +8 pad: 80B stride -> ~2-way banks
  __shared__ u16 Ws[64][40];
  int m0 = blockIdx.y * 128, n0 = blockIdx.x * 64;
  int t = threadIdx.x;
  int w = t >> 6, lane = t & 63, g = lane >> 4, l15 = lane & 15;
  int r0 = (w >> 1) * 64, c0 = (w & 1) * 32;
  f32x4 acc[4][2] = {};
  int ar = t >> 1, ac = (t & 1) * 16;
  int wr = t >> 2, wc = (t & 3) * 8;
  for(int kt = 0; kt < K/32; ++kt){
    __syncthreads();
    const uint4* ap = (const uint4*)(A + (size_t)(m0 + ar)*K + kt*32 + ac);
    uint4 a0 = ap[0], a1 = ap[1];
    *(uint4*)&As[ar][ac]     = a0;
    *(uint4*)&As[ar][ac + 8] = a1;
    const float4* wp = (const float4*)(W + (size_t)(n0 + wr)*K + kt*32 + wc);
    float4 w0 = wp[0], w1 = wp[1];
    u32 pk[4] = { pack2(w0.x,w0.y), pack2(w0.z,w0.w), pack2(w1.x,w1.y), pack2(w1.z,w1.w) };
    *(uint4*)&Ws[wr][wc] = *(uint4*)pk;
    __syncthreads();
    bf16x8 af[4], bfr[2];
    #pragma unroll
    for(int m = 0; m < 4; ++m) af[m] = *(const bf16x8*)&As[r0 + m*16 + l15][g*8];
    #pragma unroll
    for(int n = 0; n < 2; ++n) bfr[n] = *(const bf16x8*)&Ws[c0 + n*16 + l15][g*8];
    #pragma unroll
    for(int m = 0; m < 4; ++m)
      #pragma unroll
      for(int n = 0; n < 2; ++n)
        acc[m][n] = __builtin_amdgcn_mfma_f32_16x16x32_bf16(af[m], bfr[n], acc[m][n], 0, 0, 0);
  }
  #pragma unroll
  for(int m = 0; m < 4; ++m){
    #pragma unroll
    for(int n = 0; n < 2; ++n){
      int ng = n0 + c0 + n*16 + l15;
      float bv = bias ? bias[ng] : 0.f;
      #pragma unroll
      for(int i = 0; i < 4; ++i){
        int mg = m0 + r0 + m*16 + g*4 + i;
        float v = acc[m][n][i] + bv;
        if constexpr (MODE == 0){
          ((u16*)outp)[(size_t)mg*N + ng] = f2bf(v);
        } else if constexpr (MODE == 1){
          int b = mg >> 10, s = mg & 1023;
          ((u16*)outp)[((size_t)b*D + ng)*S + s] = f2bf(v);
        } else {
          ((float*)outp)[(size_t)mg*N + ng] = resid[(size_t)mg*N + ng] + v;
        }
      }
    }
  }
}

// ---------------------------------------------------------------- fused attention
// MODE 0: SDPA + self bias; MODE 1: SDPA + cross bias; MODE 2: pool + self bias
// one wave per (b, h, 16-row q-tile); swapped QK^T (St[key][q]); 32-key chunks
template<int MODE>
__global__ __launch_bounds__(64) void attn_kernel(const u16* __restrict__ Q,
    const u16* __restrict__ Kb, const u16* __restrict__ Vt,
    const float* __restrict__ aproj, const int* __restrict__ segd,
    const float* __restrict__ gate, u16* __restrict__ out){
  int qt = blockIdx.x;
  int bh = blockIdx.y; int b = bh >> 4, h = bh & 15;
  int lane = threadIdx.x, g = lane >> 4, l15 = lane & 15;
  int q = qt*16 + l15;
  float hs = exp2f(-(float)(h + 1) * 0.5f);
  int sdq = segd[b*S + q];
  int seg_q = sdq >> 2, mq = sdq & 1;
  bf16x8 qf[2];
  if constexpr (MODE != 2){
    #pragma unroll
    for(int dc = 0; dc < 2; ++dc)
      qf[dc] = *(const bf16x8*)&Q[((size_t)(b*S + q))*D + h*DK + dc*32 + g*8];
  }
  f32x4 oacc[4] = {};
  float mrun = NEGF, lsum = 0.f;
  int nc = (qt + 2) >> 1;
  for(int kc = 0; kc < nc; ++kc){
    int k0 = kc * 32;
    float sv[8];
    if constexpr (MODE != 2){
      f32x4 slo = {}, shi = {};
      #pragma unroll
      for(int dc = 0; dc < 2; ++dc){
        bf16x8 klo = *(const bf16x8*)&Kb[((size_t)(b*S + k0 + l15))*D + h*DK + dc*32 + g*8];
        slo = __builtin_amdgcn_mfma_f32_16x16x32_bf16(klo, qf[dc], slo, 0, 0, 0);
        bf16x8 khi = *(const bf16x8*)&Kb[((size_t)(b*S + k0 + 16 + l15))*D + h*DK + dc*32 + g*8];
        shi = __builtin_amdgcn_mfma_f32_16x16x32_bf16(khi, qf[dc], shi, 0, 0, 0);
      }
      #pragma unroll
      for(int i = 0; i < 4; ++i){ sv[i] = slo[i]*0.125f; sv[4+i] = shi[i]*0.125f; }
    } else {
      #pragma unroll
      for(int i = 0; i < 4; ++i){
        sv[i]   = aproj[(size_t)(b*S + k0 + g*4 + i)*H + h];
        sv[4+i] = aproj[(size_t)(b*S + k0 + 16 + g*4 + i)*H + h];
      }
    }
    // bias + mask (key = k0 + half*16 + 4g + i; col q is lane-uniform)
    #pragma unroll
    for(int half = 0; half < 2; ++half){
      #pragma unroll
      for(int i = 0; i < 4; ++i){
        int key = k0 + half*16 + g*4 + i;
        int sdk = segd[b*S + key];
        bool ok; float val;
        if constexpr (MODE == 1){
          ok = (key <= q) && ((key == q) || ((sdk >> 1) & 1));
          val = (float)((sdk >> 2) - seg_q);
        } else {
          ok = (key <= q) && ((key == q) || (((sdk >> 2) == seg_q) && ((sdk & 1) & mq)));
          val = (float)(key - q);
        }
        int idx = half*4 + i;
        sv[idx] = ok ? (sv[idx] + val*hs) : NEGF;
      }
    }
    // online softmax (reduce over 32 keys: 8 regs + groups via xor 16,32)
    float cm = sv[0];
    #pragma unroll
    for(int i = 1; i < 8; ++i) cm = fmaxf(cm, sv[i]);
    cm = fmaxf(cm, __shfl_xor(cm, 16));
    cm = fmaxf(cm, __shfl_xor(cm, 32));
    float mnew = fmaxf(mrun, cm);
    float fac = __expf(mrun - mnew);   // mrun finite sentinel: no NaN
    float ps = 0.f;
    #pragma unroll
    for(int i = 0; i < 8; ++i){ sv[i] = __expf(sv[i] - mnew); ps += sv[i]; }
    ps += __shfl_xor(ps, 16);
    ps += __shfl_xor(ps, 32);
    lsum = lsum * fac + ps;
    mrun = mnew;
    #pragma unroll
    for(int c = 0; c < 4; ++c)
      #pragma unroll
      for(int i = 0; i < 4; ++i) oacc[c][i] *= fac;
    // pack P^T and redistribute to B-operand layout (keys 8g+j per lane)
    u32 L0 = pack2(sv[0], sv[1]), L1 = pack2(sv[2], sv[3]);
    u32 H0 = pack2(sv[4], sv[5]), H1 = pack2(sv[6], sv[7]);
    int base = ((g & 1) * 2) * 16 + l15;
    u32 a0 = (u32)__shfl((int)L0, base),    a1 = (u32)__shfl((int)L1, base);
    u32 b0 = (u32)__shfl((int)L0, base+16), b1 = (u32)__shfl((int)L1, base+16);
    u32 c0 = (u32)__shfl((int)H0, base),    c1 = (u32)__shfl((int)H1, base);
    u32 d0 = (u32)__shfl((int)H0, base+16), d1 = (u32)__shfl((int)H1, base+16);
    bool hiSel = (g >= 2);
    union { u32 wd[4]; bf16x8 v; } pu;
    pu.wd[0] = hiSel ? c0 : a0;
    pu.wd[1] = hiSel ? c1 : a1;
    pu.wd[2] = hiSel ? d0 : b0;
    pu.wd[3] = hiSel ? d1 : b1;
    bf16x8 pf = pu.v;
    #pragma unroll
    for(int c = 0; c < 4; ++c){
      bf16x8 vf = *(const bf16x8*)&Vt[((size_t)((b*H + h)*DK + c*16 + l15))*S + k0 + g*8];
      oacc[c] = __builtin_amdgcn_mfma_f32_16x16x32_bf16(vf, pf, oacc[c], 0, 0, 0);
    }
  }
  // epilogue: scale by 1/lsum and sigmoid gate (both lane-uniform: q = l15)
  float scale = (1.f / lsum) * gate[(size_t)(b*S + q)*H + h];
  __shared__ u16 ot[16][72];  // 144B row stride: 16B-aligned b128 reads
  #pragma unroll
  for(int c = 0; c < 4; ++c)
    #pragma unroll
    for(int i = 0; i < 4; i += 2){
      u32 p = pack2(oacc[c][i] * scale, oacc[c][i+1] * scale);
      *(u32*)&ot[l15][c*16 + g*4 + i] = p;
    }
  __syncthreads();
  int r = lane >> 2, c4 = lane & 3;
  uint4 v0 = *(uint4*)&ot[r][c4*16];
  uint4 v1 = *(uint4*)&ot[r][c4*16 + 8];
  u16* op = out + ((size_t)(b*S + qt*16 + r))*D + h*DK + c4*16;
  *(uint4*)op = v0;
  *(uint4*)(op + 8) = v1;
}

} // namespace

extern "C" void kernel_launch(void* const* d_in, const int* in_sizes, int n_in,
                              void* d_out, int out_size, void* d_ws, size_t ws_size,
                              hipStream_t stream){
  (void)in_sizes; (void)n_in; (void)out_size; (void)ws_size;
  const float* states = (const float*)d_in[0];
  const int*   ids    = (const int*)d_in[1];
  float* xout = (float*)d_out;

  char* w = (char*)d_ws;
  u16* xln  = (u16*)w; w += (size_t)2048*1024*2;
  u16* qb   = (u16*)w; w += (size_t)2048*1024*2;
  u16* kb   = (u16*)w; w += (size_t)2048*1024*2;
  u16* vt   = (u16*)w; w += (size_t)2048*1024*2;
  u16* attn = (u16*)w; w += (size_t)2048*1024*2;
  float* gate  = (float*)w; w += (size_t)2048*16*4;
  float* aproj = (float*)w; w += (size_t)2048*16*4;
  int* segd = (int*)w;

  dim3 b256(256), g2048(2048);
  dim3 bgemm(256), ggemm(16, 16);
  dim3 battn(64), gattn(64, 32);

  seg_kernel<<<dim3(2), dim3(1024), 0, stream>>>(ids, segd);

  // ---- layer 0: SDPA, self bias
  ln_kernel<<<g2048, b256, 0, stream>>>(states, (const float*)d_in[2], (const float*)d_in[3], xln);
  gemm_kernel<0><<<ggemm, bgemm, 0, stream>>>(xln, (const float*)d_in[4], (const float*)d_in[5], qb, nullptr);
  gemm_kernel<0><<<ggemm, bgemm, 0, stream>>>(xln, (const float*)d_in[6], (const float*)d_in[7], kb, nullptr);
  gemm_kernel<1><<<ggemm, bgemm, 0, stream>>>(xln, (const float*)d_in[8], (const float*)d_in[9], vt, nullptr);
  headproj_kernel<true><<<g2048, b256, 0, stream>>>(xln, (const float*)d_in[10], (const float*)d_in[11], gate);
  attn_kernel<0><<<gattn, battn, 0, stream>>>(qb, kb, vt, nullptr, segd, gate, attn);
  gemm_kernel<2><<<ggemm, bgemm, 0, stream>>>(attn, (const float*)d_in[12], (const float*)d_in[13], xout, states);

  // ---- layer 1: pool, self bias
  ln_kernel<<<g2048, b256, 0, stream>>>(xout, (const float*)d_in[14], (const float*)d_in[15], xln);
  gemm_kernel<1><<<ggemm, bgemm, 0, stream>>>(xln, (const float*)d_in[17], (const float*)d_in[18], vt, nullptr);
  headproj_kernel<false><<<g2048, b256, 0, stream>>>(xln, (const float*)d_in[16], nullptr, aproj);
  headproj_kernel<true><<<g2048, b256, 0, stream>>>(xln, (const float*)d_in[19], (const float*)d_in[20], gate);
  attn_kernel<2><<<gattn, battn, 0, stream>>>(nullptr, nullptr, vt, aproj, segd, gate, attn);
  gemm_kernel<2><<<ggemm, bgemm, 0, stream>>>(attn, (const float*)d_in[21], (const float*)d_in[22], xout, xout);

  // ---- layer 2: SDPA, cross bias
  ln_kernel<<<g2048, b256, 0, stream>>>(xout, (const float*)d_in[23], (const float*)d_in[24], xln);
  gemm_kernel<0><<<ggemm, bgemm, 0, stream>>>(xln, (const float*)d_in[25], (const float*)d_in[26], qb, nullptr);
  gemm_kernel<0><<<ggemm, bgemm, 0, stream>>>(xln, (const float*)d_in[27], (const float*)d_in[28], kb, nullptr);
  gemm_kernel<1><<<ggemm, bgemm, 0, stream>>>(xln, (const float*)d_in[29], (const float*)d_in[30], vt, nullptr);
  headproj_kernel<true><<<g2048, b256, 0, stream>>>(xln, (const float*)d_in[31], (const float*)d_in[32], gate);
  attn_kernel<1><<<gattn, battn, 0, stream>>>(qb, kb, vt, nullptr, segd, gate, attn);
  gemm_kernel<2><<<ggemm, bgemm, 0, stream>>>(attn, (const float*)d_in[33], (const float*)d_in[34], xout, xout);
}

// Round 2
// 495.600 us; speedup vs baseline: 1.6208x; 1.6208x over previous
//
#include <hip/hip_runtime.h>

typedef unsigned short u16;
typedef unsigned int u32;
typedef __attribute__((ext_vector_type(8))) short bf16x8;
typedef __attribute__((ext_vector_type(4))) float f32x4;

namespace {

constexpr int S = 1024, D = 1024, H = 16, DK = 64;
constexpr float NEGF = -1e30f;

__device__ __forceinline__ u16 f2bf(float f){
  u32 u = __builtin_bit_cast(u32, f);
  u32 r = (u + 0x7fffu + ((u >> 16) & 1u)) >> 16;
  return (u16)r;
}
__device__ __forceinline__ float bf2f(u16 h){
  u32 u = ((u32)h) << 16;
  return __builtin_bit_cast(float, u);
}
__device__ __forceinline__ u32 pack2(float a, float b){
  return (u32)f2bf(a) | ((u32)f2bf(b) << 16);
}
__device__ __forceinline__ void glds16(const u16* g, u16* l){
  __builtin_amdgcn_global_load_lds(
      (const __attribute__((address_space(1))) u32*)g,
      (__attribute__((address_space(3))) u32*)l, 16, 0, 0);
}

// ---------------------------------------------------------------- weight f32->bf16
struct CvtArgs { const float* src[10]; u16* dst[10]; };
__global__ __launch_bounds__(256) void cvt_kernel(CvtArgs a){
  int m = blockIdx.y;
  const float* s = a.src[m];
  u16* d = a.dst[m];
  int i = (blockIdx.x * 256 + threadIdx.x) * 8;
  float4 v0 = *(const float4*)(s + i), v1 = *(const float4*)(s + i + 4);
  u32 p[4] = { pack2(v0.x,v0.y), pack2(v0.z,v0.w), pack2(v1.x,v1.y), pack2(v1.z,v1.w) };
  *(uint4*)(d + i) = *(uint4*)p;
}

// ---------------------------------------------------------------- seg scan
__global__ void seg_kernel(const int* __restrict__ ids, int* __restrict__ segd){
  __shared__ int sc[1024];
  int b = blockIdx.x, t = threadIdx.x;
  int id = ids[b*S + t];
  sc[t] = (id == 1) ? 1 : 0;
  __syncthreads();
  for(int off = 1; off < 1024; off <<= 1){
    int add = (t >= off) ? sc[t - off] : 0;
    __syncthreads();
    sc[t] += add;
    __syncthreads();
  }
  int seg = sc[t];
  segd[b*S + t] = (seg << 2) | ((id == 2) ? 2 : 0) | ((id != 0) ? 1 : 0);
}

// ---------------------------------------------------------------- layernorm
__global__ __launch_bounds__(256) void ln_kernel(const float* __restrict__ x,
    const float* __restrict__ w, const float* __restrict__ bias, u16* __restrict__ out){
  int row = blockIdx.x, t = threadIdx.x;
  float4 v = ((const float4*)(x + (size_t)row*D))[t];
  float s = v.x + v.y + v.z + v.w;
  float q = v.x*v.x + v.y*v.y + v.z*v.z + v.w*v.w;
  for(int off = 32; off >= 1; off >>= 1){ s += __shfl_down(s, off); q += __shfl_down(q, off); }
  __shared__ float ls[4], lq[4];
  int wv = t >> 6, ln = t & 63;
  if(ln == 0){ ls[wv] = s; lq[wv] = q; }
  __syncthreads();
  s = ls[0] + ls[1] + ls[2] + ls[3];
  q = lq[0] + lq[1] + lq[2] + lq[3];
  float mean = s * (1.f/D);
  float var  = q * (1.f/D) - mean*mean;
  float rs = rsqrtf(var + 1e-5f);
  float4 wv4 = ((const float4*)w)[t];
  float4 bv4 = ((const float4*)bias)[t];
  ushort4 o;
  o.x = f2bf((v.x-mean)*rs*wv4.x + bv4.x);
  o.y = f2bf((v.y-mean)*rs*wv4.y + bv4.y);
  o.z = f2bf((v.z-mean)*rs*wv4.z + bv4.z);
  o.w = f2bf((v.w-mean)*rs*wv4.w + bv4.w);
  *(ushort4*)(out + (size_t)row*D + t*4) = o;
}

// ---------------------------------------------------------------- head proj -> transposed [b,h,s]
template<bool SIG>
__global__ __launch_bounds__(256) void headproj_kernel(const u16* __restrict__ xln,
    const float* __restrict__ w, const float* __restrict__ bias, float* __restrict__ out){
  __shared__ u16 xrow[D];
  int row = blockIdx.x, t = threadIdx.x;
  ((ushort4*)xrow)[t] = ((const ushort4*)(xln + (size_t)row*D))[t];
  __syncthreads();
  int h = t >> 4, sg = t & 15;
  const u16* xp = xrow + sg*64;
  const float* wp = w + (size_t)h*D + sg*64;
  float acc = 0.f;
  #pragma unroll
  for(int c = 0; c < 64; ++c) acc += bf2f(xp[c]) * wp[c];
  for(int off = 1; off < 16; off <<= 1) acc += __shfl_xor(acc, off);
  if(sg == 0){
    float r = acc + (bias ? bias[h] : 0.f);
    int b = row >> 10, s = row & 1023;
    out[((size_t)(b*H + h) << 10) + s] = SIG ? (1.f/(1.f + __expf(-r))) : r;
  }
}

// ---------------------------------------------------------------- GEMM core helpers
// fused QKV: A[2048,1024]bf16 @ {Wq,Wk,Wv}[1024,1024]bf16^T ; BM=128 BN=128
__global__ __launch_bounds__(256) void gemm_qkv(const u16* __restrict__ A,
    const u16* __restrict__ Wq, const u16* __restrict__ Wk, const u16* __restrict__ Wv,
    const float* __restrict__ bq, const float* __restrict__ bk, const float* __restrict__ bv,
    u16* __restrict__ outq, u16* __restrict__ outk, u16* __restrict__ outvt){
  constexpr int K = 1024;
  __shared__ alignas(16) u16 As[128*32];
  __shared__ alignas(16) u16 Bs[128*32];
  int m0 = blockIdx.y * 128, n0g = blockIdx.x * 128;
  int mat = n0g >> 10, n0 = n0g & 1023;
  const u16* W = (mat == 0) ? Wq : (mat == 1) ? Wk : Wv;
  const float* bias = (mat == 0) ? bq : (mat == 1) ? bk : bv;
  int t = threadIdx.x, w = t >> 6, lane = t & 63, g = lane >> 4, l15 = lane & 15;
  int r0 = (w >> 1) * 64, c0 = (w & 1) * 64;
  f32x4 acc[4][4] = {};
  int srow = lane >> 2, schk = (lane & 3) * 8;
  for(int kt = 0; kt < K/32; ++kt){
    const u16* Ag = A + (size_t)m0*K + kt*32;
    const u16* Wg = W + (size_t)n0*K + kt*32;
    #pragma unroll
    for(int j = 0; j < 2; ++j){
      int row = w*32 + j*16 + srow;
      glds16(Ag + (size_t)row*K + schk, &As[(w*32 + j*16)*32]);
      glds16(Wg + (size_t)row*K + schk, &Bs[(w*32 + j*16)*32]);
    }
    __syncthreads();
    bf16x8 af[4], bfr[4];
    #pragma unroll
    for(int m = 0; m < 4; ++m) af[m] = *(const bf16x8*)&As[(r0 + m*16 + l15)*32 + g*8];
    #pragma unroll
    for(int n = 0; n < 4; ++n) bfr[n] = *(const bf16x8*)&Bs[(c0 + n*16 + l15)*32 + g*8];
    #pragma unroll
    for(int m = 0; m < 4; ++m)
      #pragma unroll
      for(int n = 0; n < 4; ++n)
        acc[m][n] = __builtin_amdgcn_mfma_f32_16x16x32_bf16(af[m], bfr[n], acc[m][n], 0, 0, 0);
    __syncthreads();
  }
  #pragma unroll
  for(int m = 0; m < 4; ++m){
    #pragma unroll
    for(int n = 0; n < 4; ++n){
      int ng = n0 + c0 + n*16 + l15;
      float bv4 = bias[ng];
      #pragma unroll
      for(int i = 0; i < 4; ++i){
        int mg = m0 + r0 + m*16 + g*4 + i;
        float v = acc[m][n][i] + bv4;
        if(mat < 2){
          u16* o = (mat == 0) ? outq : outk;
          o[(size_t)mg*D + ng] = f2bf(v);
        } else {
          int b = mg >> 10, s = mg & 1023;
          outvt[((size_t)(b*D + ng))*S + s] = f2bf(v);
        }
      }
    }
  }
}

// generic GEMM BM=128 BN=64. MODE 1: bf16 transposed (vt); MODE 2: f32 + resid
template<int MODE>
__global__ __launch_bounds__(256) void gemm_gen(const u16* __restrict__ A,
    const u16* __restrict__ W, const float* __restrict__ bias,
    void* __restrict__ outp, const float* __restrict__ resid){
  constexpr int K = 1024, N = 1024;
  __shared__ alignas(16) u16 As[128*32];
  __shared__ alignas(16) u16 Bs[64*32];
  int m0 = blockIdx.y * 128, n0 = blockIdx.x * 64;
  int t = threadIdx.x, w = t >> 6, lane = t & 63, g = lane >> 4, l15 = lane & 15;
  int r0 = w * 32;
  f32x4 acc[2][4] = {};
  int srow = lane >> 2, schk = (lane & 3) * 8;
  for(int kt = 0; kt < K/32; ++kt){
    const u16* Ag = A + (size_t)m0*K + kt*32;
    const u16* Wg = W + (size_t)n0*K + kt*32;
    #pragma unroll
    for(int j = 0; j < 2; ++j){
      int row = w*32 + j*16 + srow;
      glds16(Ag + (size_t)row*K + schk, &As[(w*32 + j*16)*32]);
    }
    {
      int row = w*16 + srow;
      glds16(Wg + (size_t)row*K + schk, &Bs[(w*16)*32]);
    }
    __syncthreads();
    bf16x8 af[2], bfr[4];
    #pragma unroll
    for(int m = 0; m < 2; ++m) af[m] = *(const bf16x8*)&As[(r0 + m*16 + l15)*32 + g*8];
    #pragma unroll
    for(int n = 0; n < 4; ++n) bfr[n] = *(const bf16x8*)&Bs[(n*16 + l15)*32 + g*8];
    #pragma unroll
    for(int m = 0; m < 2; ++m)
      #pragma unroll
      for(int n = 0; n < 4; ++n)
        acc[m][n] = __builtin_amdgcn_mfma_f32_16x16x32_bf16(af[m], bfr[n], acc[m][n], 0, 0, 0);
    __syncthreads();
  }
  #pragma unroll
  for(int m = 0; m < 2; ++m){
    #pragma unroll
    for(int n = 0; n < 4; ++n){
      int ng = n0 + n*16 + l15;
      float bv = bias ? bias[ng] : 0.f;
      #pragma unroll
      for(int i = 0; i < 4; ++i){
        int mg = m0 + r0 + m*16 + g*4 + i;
        float v = acc[m][n][i] + bv;
        if constexpr (MODE == 1){
          int b = mg >> 10, s = mg & 1023;
          ((u16*)outp)[((size_t)(b*D + ng))*S + s] = f2bf(v);
        } else {
          ((float*)outp)[(size_t)mg*N + ng] = resid[(size_t)mg*N + ng] + v;
        }
      }
    }
  }
}

// ---------------------------------------------------------------- fused attention v2
// 256 threads = 4 waves; wave w handles q-tile qt = w*16 + blockIdx.x for (b,h)=blockIdx.y
// KBLK=64, register double-buffered K, segd (and pool scores) staged in LDS
__device__ __forceinline__ bf16x8 repack8(const float* s, int g, int l15){
  u32 L0 = pack2(s[0], s[1]), L1 = pack2(s[2], s[3]);
  u32 H0 = pack2(s[4], s[5]), H1 = pack2(s[6], s[7]);
  int base = ((g & 1) * 2) * 16 + l15;
  u32 a0 = (u32)__shfl((int)L0, base),    a1 = (u32)__shfl((int)L1, base);
  u32 b0 = (u32)__shfl((int)L0, base+16), b1 = (u32)__shfl((int)L1, base+16);
  u32 c0 = (u32)__shfl((int)H0, base),    c1 = (u32)__shfl((int)H1, base);
  u32 d0 = (u32)__shfl((int)H0, base+16), d1 = (u32)__shfl((int)H1, base+16);
  bool hi = g >= 2;
  union { u32 wd[4]; bf16x8 v; } pu;
  pu.wd[0] = hi ? c0 : a0;
  pu.wd[1] = hi ? c1 : a1;
  pu.wd[2] = hi ? d0 : b0;
  pu.wd[3] = hi ? d1 : b1;
  return pu.v;
}

template<int MODE>   // 0: SDPA self; 1: SDPA cross; 2: pool self
__global__ __launch_bounds__(256) void attn2_kernel(const u16* __restrict__ Q,
    const u16* __restrict__ Kb, const u16* __restrict__ Vt,
    const float* __restrict__ aprojT, const int* __restrict__ segd,
    const float* __restrict__ gateT, u16* __restrict__ out){
  __shared__ int segL[1024];
  __shared__ float apL[1024];
  __shared__ u16 ot[4][16][72];
  int bh = blockIdx.y, b = bh >> 4, h = bh & 15;
  int t = threadIdx.x, w = t >> 6, lane = t & 63, g = lane >> 4, l15 = lane & 15;
  { int4 v = ((const int4*)(segd + b*S))[t]; *(int4*)&segL[t*4] = v; }
  if constexpr (MODE == 2){
    float4 v = ((const float4*)(aprojT + ((size_t)bh << 10)))[t];
    *(float4*)&apL[t*4] = v;
  }
  __syncthreads();
  int qt = w*16 + blockIdx.x;
  int q = qt*16 + l15;
  float hs = exp2f(-(float)(h + 1) * 0.5f);
  int sdq = segL[q];
  int seg_q = sdq >> 2, mq = sdq & 1;
  bf16x8 qf0 = {}, qf1 = {};
  if constexpr (MODE != 2){
    const u16* qp = Q + ((size_t)(b*S + q))*D + h*DK + g*8;
    qf0 = *(const bf16x8*)qp;
    qf1 = *(const bf16x8*)(qp + 32);
  }
  f32x4 oacc[4] = {};
  float mrun = NEGF, lsum = 0.f;
  int nc = (qt*16 + 79) >> 6;
  const u16* Kbase = Kb + ((size_t)b*S)*D + h*DK + g*8;
  const u16* Vbase = Vt + ((size_t)(bh*DK + l15))*S;

  auto LOADK = [&](bf16x8 (&kb)[8], int kc){
    if constexpr (MODE != 2){
      const u16* p = Kbase + (size_t)(kc*64)*D;
      #pragma unroll
      for(int r = 0; r < 4; ++r){
        const u16* pr = p + (size_t)(r*16 + l15)*D;
        kb[r*2]   = *(const bf16x8*)pr;
        kb[r*2+1] = *(const bf16x8*)(pr + 32);
      }
    }
  };
  auto STEP = [&](bf16x8 (&kb)[8], int kc){
    int k0 = kc*64;
    bf16x8 vr[8];
    #pragma unroll
    for(int c = 0; c < 4; ++c){
      const u16* vp = Vbase + (size_t)(c*16)*S + k0 + g*8;
      vr[c*2]   = *(const bf16x8*)vp;
      vr[c*2+1] = *(const bf16x8*)(vp + 32);
    }
    float sv[16];
    if constexpr (MODE != 2){
      #pragma unroll
      for(int r = 0; r < 4; ++r){
        f32x4 sa = {};
        sa = __builtin_amdgcn_mfma_f32_16x16x32_bf16(kb[r*2],   qf0, sa, 0, 0, 0);
        sa = __builtin_amdgcn_mfma_f32_16x16x32_bf16(kb[r*2+1], qf1, sa, 0, 0, 0);
        #pragma unroll
        for(int i = 0; i < 4; ++i) sv[r*4+i] = sa[i] * 0.125f;
      }
    } else {
      #pragma unroll
      for(int r = 0; r < 4; ++r){
        float4 a4 = *(const float4*)&apL[k0 + r*16 + g*4];
        sv[r*4+0] = a4.x; sv[r*4+1] = a4.y; sv[r*4+2] = a4.z; sv[r*4+3] = a4.w;
      }
    }
    #pragma unroll
    for(int r = 0; r < 4; ++r){
      int4 sd4 = *(const int4*)&segL[k0 + r*16 + g*4];
      int sds[4] = { sd4.x, sd4.y, sd4.z, sd4.w };
      #pragma unroll
      for(int i = 0; i < 4; ++i){
        int key = k0 + r*16 + g*4 + i;
        int sdk = sds[i];
        bool ok; float val;
        if constexpr (MODE == 1){
          ok = (key < q && (sdk & 2)) || (key == q);
          val = (float)((sdk >> 2) - seg_q);
        } else {
          ok = (key < q && ((sdk >> 2) == seg_q) && (sdk & mq & 1)) || (key == q);
          val = (float)(key - q);
        }
        sv[r*4+i] = ok ? sv[r*4+i] + val*hs : NEGF;
      }
    }
    float cm = sv[0];
    #pragma unroll
    for(int i = 1; i < 16; ++i) cm = fmaxf(cm, sv[i]);
    cm = fmaxf(cm, __shfl_xor(cm, 16));
    cm = fmaxf(cm, __shfl_xor(cm, 32));
    float mnew = fmaxf(mrun, cm);
    float fac = __expf(mrun - mnew);
    float ps = 0.f;
    #pragma unroll
    for(int i = 0; i < 16; ++i){ sv[i] = __expf(sv[i] - mnew); ps += sv[i]; }
    ps += __shfl_xor(ps, 16);
    ps += __shfl_xor(ps, 32);
    lsum = lsum * fac + ps;
    mrun = mnew;
    #pragma unroll
    for(int c = 0; c < 4; ++c)
      #pragma unroll
      for(int i = 0; i < 4; ++i) oacc[c][i] *= fac;
    #pragma unroll
    for(int ks = 0; ks < 2; ++ks){
      bf16x8 pf = repack8(&sv[ks*8], g, l15);
      #pragma unroll
      for(int c = 0; c < 4; ++c)
        oacc[c] = __builtin_amdgcn_mfma_f32_16x16x32_bf16(vr[c*2+ks], pf, oacc[c], 0, 0, 0);
    }
  };

  bf16x8 kbufA[8], kbufB[8];
  LOADK(kbufA, 0);
  int kc = 0;
  while(kc + 2 <= nc){
    LOADK(kbufB, kc + 1);
    STEP(kbufA, kc);
    if(kc + 2 < nc) LOADK(kbufA, kc + 2);
    STEP(kbufB, kc + 1);
    kc += 2;
  }
  if(kc < nc) STEP(kbufA, kc);

  float scale = (1.f / lsum) * gateT[((size_t)bh << 10) + q];
  #pragma unroll
  for(int c = 0; c < 4; ++c)
    #pragma unroll
    for(int i = 0; i < 4; i += 2){
      u32 p = pack2(oacc[c][i] * scale, oacc[c][i+1] * scale);
      *(u32*)&ot[w][l15][c*16 + g*4 + i] = p;
    }
  int r = lane >> 2, c4 = lane & 3;
  uint4 v0 = *(uint4*)&ot[w][r][c4*16];
  uint4 v1 = *(uint4*)&ot[w][r][c4*16 + 8];
  u16* op = out + ((size_t)(b*S + qt*16 + r))*D + h*DK + c4*16;
  *(uint4*)op = v0;
  *(uint4*)(op + 8) = v1;
}

} // namespace

extern "C" void kernel_launch(void* const* d_in, const int* in_sizes, int n_in,
                              void* d_out, int out_size, void* d_ws, size_t ws_size,
                              hipStream_t stream){
  (void)in_sizes; (void)n_in; (void)out_size; (void)ws_size;
  const float* states = (const float*)d_in[0];
  const int*   ids    = (const int*)d_in[1];
  float* xout = (float*)d_out;

  char* w = (char*)d_ws;
  u16* wbf[10];
  for(int i = 0; i < 10; ++i){ wbf[i] = (u16*)w; w += (size_t)1024*1024*2; }
  u16* xln  = (u16*)w; w += (size_t)2048*1024*2;
  u16* qb   = (u16*)w; w += (size_t)2048*1024*2;
  u16* kb   = (u16*)w; w += (size_t)2048*1024*2;
  u16* vt   = (u16*)w; w += (size_t)2048*1024*2;
  u16* attn = (u16*)w; w += (size_t)2048*1024*2;
  float* gateT  = (float*)w; w += (size_t)2048*16*4;
  float* aprojT = (float*)w; w += (size_t)2048*16*4;
  int* segd = (int*)w;

  // weight indices: l0 qw4 kw6 vw8 ow12 | l1 vw17 ow21 | l2 qw25 kw27 vw29 ow33
  const int widx[10] = {4, 6, 8, 12, 17, 21, 25, 27, 29, 33};
  CvtArgs ca;
  for(int i = 0; i < 10; ++i){ ca.src[i] = (const float*)d_in[widx[i]]; ca.dst[i] = wbf[i]; }
  cvt_kernel<<<dim3(512, 10), dim3(256), 0, stream>>>(ca);
  seg_kernel<<<dim3(2), dim3(1024), 0, stream>>>(ids, segd);

  dim3 b256(256), g2048(2048);
  dim3 gqkv(24, 16), ggen(16, 16), gattn(16, 32);

  // ---- layer 0: SDPA, self bias
  ln_kernel<<<g2048, b256, 0, stream>>>(states, (const float*)d_in[2], (const float*)d_in[3], xln);
  gemm_qkv<<<gqkv, b256, 0, stream>>>(xln, wbf[0], wbf[1], wbf[2],
      (const float*)d_in[5], (const float*)d_in[7], (const float*)d_in[9], qb, kb, vt);
  headproj_kernel<true><<<g2048, b256, 0, stream>>>(xln, (const float*)d_in[10], (const float*)d_in[11], gateT);
  attn2_kernel<0><<<gattn, b256, 0, stream>>>(qb, kb, vt, nullptr, segd, gateT, attn);
  gemm_gen<2><<<ggen, b256, 0, stream>>>(attn, wbf[3], (const float*)d_in[13], xout, states);

  // ---- layer 1: pool, self bias
  ln_kernel<<<g2048, b256, 0, stream>>>(xout, (const float*)d_in[14], (const float*)d_in[15], xln);
  gemm_gen<1><<<ggen, b256, 0, stream>>>(xln, wbf[4], (const float*)d_in[18], vt, nullptr);
  headproj_kernel<false><<<g2048, b256, 0, stream>>>(xln, (const float*)d_in[16], nullptr, aprojT);
  headproj_kernel<true><<<g2048, b256, 0, stream>>>(xln, (const float*)d_in[19], (const float*)d_in[20], gateT);
  attn2_kernel<2><<<gattn, b256, 0, stream>>>(nullptr, nullptr, vt, aprojT, segd, gateT, attn);
  gemm_gen<2><<<ggen, b256, 0, stream>>>(attn, wbf[5], (const float*)d_in[22], xout, xout);

  // ---- layer 2: SDPA, cross bias
  ln_kernel<<<g2048, b256, 0, stream>>>(xout, (const float*)d_in[23], (const float*)d_in[24], xln);
  gemm_qkv<<<gqkv, b256, 0, stream>>>(xln, wbf[6], wbf[7], wbf[8],
      (const float*)d_in[26], (const float*)d_in[28], (const float*)d_in[30], qb, kb, vt);
  headproj_kernel<true><<<g2048, b256, 0, stream>>>(xln, (const float*)d_in[31], (const float*)d_in[32], gateT);
  attn2_kernel<1><<<gattn, b256, 0, stream>>>(qb, kb, vt, nullptr, segd, gateT, attn);
  gemm_gen<2><<<ggen, b256, 0, stream>>>(attn, wbf[9], (const float*)d_in[34], xout, xout);
}